// Round 1
// baseline (1230.682 us; speedup 1.0000x reference)
//
#include <hip/hip_runtime.h>

#define CH 64

// ---------------- GEMM: out[n][64] = (relu?)(h[n][K]) @ W[K][64] ----------------
// 64 rows per block, 256 threads: thread = (rq = t>>4 -> rows 4*rq..+3, cg = t&15 -> channels 4*cg..+3)
template<int K, bool RELU>
__global__ __launch_bounds__(256) void gemm_kernel(
    const float* __restrict__ h, const float* __restrict__ W,
    float* __restrict__ out, int n)
{
    constexpr int LDH = K + 4;                 // pad to break bank conflicts on row-strided reads
    __shared__ float Ws[K * CH];
    __shared__ float Hs[64 * LDH];

    const int t    = threadIdx.x;
    const int row0 = blockIdx.x * 64;

    // stage W (flat copy, contiguous)
    for (int i = t * 4; i < K * CH; i += 256 * 4) {
        *(float4*)&Ws[i] = *(const float4*)&W[i];
    }
    // stage H tile (64 x K), optional fused relu, zero-fill OOB rows
    for (int i = t * 4; i < 64 * K; i += 256 * 4) {
        int r = i / K;
        int k = i % K;                          // multiple of 4 -> aligned float4
        int row = row0 + r;
        float4 v;
        if (row < n) {
            v = *(const float4*)&h[(size_t)row * K + k];
            if (RELU) {
                v.x = fmaxf(v.x, 0.f); v.y = fmaxf(v.y, 0.f);
                v.z = fmaxf(v.z, 0.f); v.w = fmaxf(v.w, 0.f);
            }
        } else {
            v = make_float4(0.f, 0.f, 0.f, 0.f);
        }
        *(float4*)&Hs[r * LDH + k] = v;
    }
    __syncthreads();

    const int cg = t & 15;
    const int rq = t >> 4;

    float4 acc[4];
    #pragma unroll
    for (int i = 0; i < 4; ++i) acc[i] = make_float4(0.f, 0.f, 0.f, 0.f);

    for (int k = 0; k < K; k += 4) {
        float4 w[4];
        #pragma unroll
        for (int kk = 0; kk < 4; ++kk)
            w[kk] = *(float4*)&Ws[(k + kk) * CH + cg * 4];
        #pragma unroll
        for (int i = 0; i < 4; ++i) {
            float4 hv = *(float4*)&Hs[(rq * 4 + i) * LDH + k];
            float hs[4] = {hv.x, hv.y, hv.z, hv.w};
            #pragma unroll
            for (int kk = 0; kk < 4; ++kk) {
                acc[i].x = fmaf(hs[kk], w[kk].x, acc[i].x);
                acc[i].y = fmaf(hs[kk], w[kk].y, acc[i].y);
                acc[i].z = fmaf(hs[kk], w[kk].z, acc[i].z);
                acc[i].w = fmaf(hs[kk], w[kk].w, acc[i].w);
            }
        }
    }

    #pragma unroll
    for (int i = 0; i < 4; ++i) {
        int row = row0 + rq * 4 + i;
        if (row < n)
            *(float4*)&out[(size_t)row * CH + cg * 4] = acc[i];
    }
}

// ---------------- init: agg[n][64] = broadcast(b[64]) ----------------
__global__ __launch_bounds__(256) void init_bias_kernel(
    float* __restrict__ agg, const float* __restrict__ b, int n)
{
    int gi = blockIdx.x * blockDim.x + threadIdx.x;   // one float4 per thread
    int total = n * (CH / 4);
    if (gi >= total) return;
    float4 bv = *(const float4*)&b[(gi & 15) * 4];
    *(float4*)&agg[(size_t)gi * 4] = bv;
}

// ---------------- scatter: agg[dst[e]][c] += hw[src[e]][c] ----------------
// one wave per edge (64 lanes = 64 channels); 4 edges per 256-thread block
__global__ __launch_bounds__(256) void scatter_kernel(
    const float* __restrict__ hw, const int* __restrict__ src,
    const int* __restrict__ dst, float* __restrict__ agg, int E)
{
    int c = threadIdx.x & 63;
    int e = blockIdx.x * 4 + (threadIdx.x >> 6);
    if (e >= E) return;
    int s = src[e];
    int d = dst[e];
    float v = hw[(size_t)s * CH + c];
    atomicAdd(&agg[(size_t)d * CH + c], v);
}

extern "C" void kernel_launch(void* const* d_in, const int* in_sizes, int n_in,
                              void* d_out, int out_size, void* d_ws, size_t ws_size,
                              hipStream_t stream) {
    const float* x    = (const float*)d_in[0];
    const int*   esrc = (const int*)  d_in[1];
    const int*   edst = (const int*)  d_in[2];
    const float* W1   = (const float*)d_in[3];
    const float* b1   = (const float*)d_in[4];
    const float* W2   = (const float*)d_in[5];
    const float* b2   = (const float*)d_in[6];
    const float* W3   = (const float*)d_in[7];
    const float* b3   = (const float*)d_in[8];
    float* out = (float*)d_out;

    const int N = in_sizes[0] / 128;
    const int E = in_sizes[1];

    float* buf0 = (float*)d_ws;                 // transformed features (h @ W)
    float* buf1 = buf0 + (size_t)N * CH;        // aggregation target

    dim3 blk(256);
    int gemmGrid = (N + 63) / 64;
    int initGrid = (N * (CH / 4) + 255) / 256;
    int scatGrid = (E + 3) / 4;

    // layer 1: hw = x@W1 ; agg = b1 + scatter ; (relu fused into next gemm load)
    gemm_kernel<128, false><<<gemmGrid, blk, 0, stream>>>(x, W1, buf0, N);
    init_bias_kernel<<<initGrid, blk, 0, stream>>>(buf1, b1, N);
    scatter_kernel<<<scatGrid, blk, 0, stream>>>(buf0, esrc, edst, buf1, E);

    // layer 2
    gemm_kernel<64, true><<<gemmGrid, blk, 0, stream>>>(buf1, W2, buf0, N);
    init_bias_kernel<<<initGrid, blk, 0, stream>>>(buf1, b2, N);
    scatter_kernel<<<scatGrid, blk, 0, stream>>>(buf0, esrc, edst, buf1, E);

    // layer 3: aggregate straight into d_out (pre-initialized with b3)
    gemm_kernel<64, true><<<gemmGrid, blk, 0, stream>>>(buf1, W3, buf0, N);
    init_bias_kernel<<<initGrid, blk, 0, stream>>>(out, b3, N);
    scatter_kernel<<<scatGrid, blk, 0, stream>>>(buf0, esrc, edst, out, E);
}

// Round 2
// 571.520 us; speedup vs baseline: 2.1533x; 2.1533x over previous
//
#include <hip/hip_runtime.h>

#define CH 64

// ---------------- GEMM: out[n][64] = (relu?)(h[n][K]) @ W[K][64] ----------------
template<int K, bool RELU>
__global__ __launch_bounds__(256) void gemm_kernel(
    const float* __restrict__ h, const float* __restrict__ W,
    float* __restrict__ out, int n)
{
    constexpr int LDH = K + 4;
    __shared__ float Ws[K * CH];
    __shared__ float Hs[64 * LDH];

    const int t    = threadIdx.x;
    const int row0 = blockIdx.x * 64;

    for (int i = t * 4; i < K * CH; i += 256 * 4) {
        *(float4*)&Ws[i] = *(const float4*)&W[i];
    }
    for (int i = t * 4; i < 64 * K; i += 256 * 4) {
        int r = i / K;
        int k = i % K;
        int row = row0 + r;
        float4 v;
        if (row < n) {
            v = *(const float4*)&h[(size_t)row * K + k];
            if (RELU) {
                v.x = fmaxf(v.x, 0.f); v.y = fmaxf(v.y, 0.f);
                v.z = fmaxf(v.z, 0.f); v.w = fmaxf(v.w, 0.f);
            }
        } else {
            v = make_float4(0.f, 0.f, 0.f, 0.f);
        }
        *(float4*)&Hs[r * LDH + k] = v;
    }
    __syncthreads();

    const int cg = t & 15;
    const int rq = t >> 4;

    float4 acc[4];
    #pragma unroll
    for (int i = 0; i < 4; ++i) acc[i] = make_float4(0.f, 0.f, 0.f, 0.f);

    for (int k = 0; k < K; k += 4) {
        float4 w[4];
        #pragma unroll
        for (int kk = 0; kk < 4; ++kk)
            w[kk] = *(float4*)&Ws[(k + kk) * CH + cg * 4];
        #pragma unroll
        for (int i = 0; i < 4; ++i) {
            float4 hv = *(float4*)&Hs[(rq * 4 + i) * LDH + k];
            float hs[4] = {hv.x, hv.y, hv.z, hv.w};
            #pragma unroll
            for (int kk = 0; kk < 4; ++kk) {
                acc[i].x = fmaf(hs[kk], w[kk].x, acc[i].x);
                acc[i].y = fmaf(hs[kk], w[kk].y, acc[i].y);
                acc[i].z = fmaf(hs[kk], w[kk].z, acc[i].z);
                acc[i].w = fmaf(hs[kk], w[kk].w, acc[i].w);
            }
        }
    }

    #pragma unroll
    for (int i = 0; i < 4; ++i) {
        int row = row0 + rq * 4 + i;
        if (row < n)
            *(float4*)&out[(size_t)row * CH + cg * 4] = acc[i];
    }
}

// ---------------- CSR build ----------------
__global__ __launch_bounds__(256) void hist_kernel(
    const int* __restrict__ dst, int* __restrict__ cnt, int E)
{
    int i = blockIdx.x * 256 + threadIdx.x;
    if (i < E) atomicAdd(&cnt[dst[i]], 1);
}

// per-tile (1024 counts) sums
__global__ __launch_bounds__(256) void scan_tile_sum(
    const int* __restrict__ cnt, int* __restrict__ tileSum, int N)
{
    __shared__ int red[256];
    int t = threadIdx.x;
    int base = blockIdx.x * 1024 + t * 4;
    int s = 0;
    #pragma unroll
    for (int j = 0; j < 4; ++j) {
        int i = base + j;
        if (i < N) s += cnt[i];
    }
    red[t] = s;
    __syncthreads();
    for (int off = 128; off > 0; off >>= 1) {
        if (t < off) red[t] += red[t + off];
        __syncthreads();
    }
    if (t == 0) tileSum[blockIdx.x] = red[0];
}

// serial exclusive scan of tile sums (T ~ 98, trivial)
__global__ __launch_bounds__(64) void scan_tile_off(
    const int* __restrict__ tileSum, int* __restrict__ tileOff, int T)
{
    if (threadIdx.x == 0 && blockIdx.x == 0) {
        int acc = 0;
        for (int i = 0; i < T; ++i) { tileOff[i] = acc; acc += tileSum[i]; }
    }
}

// per-tile exclusive scan, add tile offset, write row_start and row_next
__global__ __launch_bounds__(256) void scan_final(
    const int* __restrict__ cnt, const int* __restrict__ tileOff,
    int* __restrict__ row_start, int* __restrict__ row_next, int N)
{
    __shared__ int tsum[256];
    int t = threadIdx.x;
    int base = blockIdx.x * 1024 + t * 4;
    int c[4];
    #pragma unroll
    for (int j = 0; j < 4; ++j) {
        int i = base + j;
        c[j] = (i < N) ? cnt[i] : 0;
    }
    int local = c[0] + c[1] + c[2] + c[3];
    tsum[t] = local;
    __syncthreads();
    // Hillis-Steele inclusive scan over 256 thread sums
    for (int off = 1; off < 256; off <<= 1) {
        int v = (t >= off) ? tsum[t - off] : 0;
        __syncthreads();
        tsum[t] += v;
        __syncthreads();
    }
    int p = tsum[t] - local + tileOff[blockIdx.x];
    #pragma unroll
    for (int j = 0; j < 4; ++j) {
        int i = base + j;
        if (i < N) { row_start[i] = p; row_next[i] = p; }
        p += c[j];
    }
}

__global__ __launch_bounds__(256) void scatter_pos_kernel(
    const int* __restrict__ src, const int* __restrict__ dst,
    int* __restrict__ row_next, int* __restrict__ sorted_src, int E)
{
    int e = blockIdx.x * 256 + threadIdx.x;
    if (e >= E) return;
    int d = dst[e];
    int p = atomicAdd(&row_next[d], 1);
    sorted_src[p] = src[e];
}

// ---------------- aggregate: out[d][c] = b[c] + sum_{e in seg(d)} hw[src[e]][c] ----------------
// one wave per node, 64 lanes = 64 channels
__global__ __launch_bounds__(256) void aggregate_kernel(
    const float* __restrict__ hw, const int* __restrict__ sorted_src,
    const int* __restrict__ row_start, const int* __restrict__ cnt,
    const float* __restrict__ b, float* __restrict__ out, int N)
{
    int lane = threadIdx.x & 63;
    int node = blockIdx.x * 4 + (threadIdx.x >> 6);
    if (node >= N) return;
    int s = row_start[node];
    int n = cnt[node];
    int end = s + n;

    float a0 = b[lane], a1 = 0.f, a2 = 0.f, a3 = 0.f;
    int e = s;
    for (; e + 4 <= end; e += 4) {
        int i0 = sorted_src[e];
        int i1 = sorted_src[e + 1];
        int i2 = sorted_src[e + 2];
        int i3 = sorted_src[e + 3];
        a0 += hw[(size_t)i0 * CH + lane];
        a1 += hw[(size_t)i1 * CH + lane];
        a2 += hw[(size_t)i2 * CH + lane];
        a3 += hw[(size_t)i3 * CH + lane];
    }
    for (; e < end; ++e)
        a0 += hw[(size_t)sorted_src[e] * CH + lane];

    out[(size_t)node * CH + lane] = (a0 + a1) + (a2 + a3);
}

extern "C" void kernel_launch(void* const* d_in, const int* in_sizes, int n_in,
                              void* d_out, int out_size, void* d_ws, size_t ws_size,
                              hipStream_t stream) {
    const float* x    = (const float*)d_in[0];
    const int*   esrc = (const int*)  d_in[1];
    const int*   edst = (const int*)  d_in[2];
    const float* W1   = (const float*)d_in[3];
    const float* b1   = (const float*)d_in[4];
    const float* W2   = (const float*)d_in[5];
    const float* b2   = (const float*)d_in[6];
    const float* W3   = (const float*)d_in[7];
    const float* b3   = (const float*)d_in[8];
    float* out = (float*)d_out;

    const int N = in_sizes[0] / 128;
    const int E = in_sizes[1];
    const int T = (N + 1023) / 1024;   // scan tiles

    // workspace layout
    char* ws = (char*)d_ws;
    float* buf0       = (float*)ws;                         ws += (size_t)N * CH * 4;  // hw
    int*   sorted_src = (int*)ws;                           ws += (size_t)E * 4;
    int*   row_start  = (int*)ws;                           ws += (size_t)N * 4;
    int*   row_next   = (int*)ws;                           ws += (size_t)N * 4;
    int*   cnt        = (int*)ws;                           ws += (size_t)N * 4;
    int*   tileSum    = (int*)ws;                           ws += (size_t)T * 4;
    int*   tileOff    = (int*)ws;                           ws += (size_t)T * 4;

    dim3 blk(256);
    int gemmGrid = (N + 63) / 64;
    int aggGrid  = (N + 3) / 4;
    int edgeGrid = (E + 255) / 256;

    // ---- CSR build (once; shared by all 3 layers) ----
    hipMemsetAsync(cnt, 0, (size_t)N * 4, stream);
    hist_kernel<<<edgeGrid, blk, 0, stream>>>(edst, cnt, E);
    scan_tile_sum<<<T, blk, 0, stream>>>(cnt, tileSum, N);
    scan_tile_off<<<1, 64, 0, stream>>>(tileSum, tileOff, T);
    scan_final<<<T, blk, 0, stream>>>(cnt, tileOff, row_start, row_next, N);
    scatter_pos_kernel<<<edgeGrid, blk, 0, stream>>>(esrc, edst, row_next, sorted_src, E);

    // ---- layer 1 ----
    gemm_kernel<128, false><<<gemmGrid, blk, 0, stream>>>(x, W1, buf0, N);
    aggregate_kernel<<<aggGrid, blk, 0, stream>>>(buf0, sorted_src, row_start, cnt, b1, out, N);
    // ---- layer 2 (relu fused into gemm load) ----
    gemm_kernel<64, true><<<gemmGrid, blk, 0, stream>>>(out, W2, buf0, N);
    aggregate_kernel<<<aggGrid, blk, 0, stream>>>(buf0, sorted_src, row_start, cnt, b2, out, N);
    // ---- layer 3 ----
    gemm_kernel<64, true><<<gemmGrid, blk, 0, stream>>>(out, W3, buf0, N);
    aggregate_kernel<<<aggGrid, blk, 0, stream>>>(buf0, sorted_src, row_start, cnt, b3, out, N);
}